// Round 1
// baseline (3049.652 us; speedup 1.0000x reference)
//
#include <hip/hip_runtime.h>
#include <math.h>

static constexpr int CH   = 112;
static constexpr int HID  = 448;
static constexpr int NPOS = 64 * 64 * 64;            // 262144 = 2^18
static constexpr long long NELEM = (long long)CH * NPOS; // 29360128

__device__ __forceinline__ float gelu_f(float x) {
    return 0.5f * x * (1.0f + erff(x * 0.70710678118654752f));
}

// mean / inv-std from accumulated (sum, sumsq)
__device__ __forceinline__ void stats_from(const double* __restrict__ S, float* mu, float* inv) {
    double m = S[0] / (double)NELEM;
    double v = S[1] / (double)NELEM - m * m;
    *mu  = (float)m;
    *inv = (float)(1.0 / sqrt(v + 1e-5));
}

// block-wide (sum, sumsq) reduction -> atomicAdd into out[0], out[1]
__device__ __forceinline__ void block_reduce2(double s, double q, double* __restrict__ out) {
    #pragma unroll
    for (int off = 32; off > 0; off >>= 1) {
        s += __shfl_down(s, off, 64);
        q += __shfl_down(q, off, 64);
    }
    __shared__ double red[16];
    int lane = threadIdx.x & 63, wv = threadIdx.x >> 6;
    int nw = blockDim.x >> 6;
    if (lane == 0) { red[wv] = s; red[wv + 8] = q; }
    __syncthreads();
    if (threadIdx.x == 0) {
        double S = 0, Q = 0;
        for (int i = 0; i < nw; i++) { S += red[i]; Q += red[i + 8]; }
        atomicAdd(out, S);
        atomicAdd(out + 1, Q);
    }
}

// ---- K1: reduce x -> S0 ----
__global__ void k_reduce(const float* __restrict__ x, double* __restrict__ S) {
    long long i0 = (long long)blockIdx.x * blockDim.x + threadIdx.x;
    long long stride = (long long)gridDim.x * blockDim.x;
    const float4* x4 = (const float4*)x;
    long long n4 = NELEM / 4;
    double s = 0, q = 0;
    for (long long i = i0; i < n4; i += stride) {
        float4 v = x4[i];
        s += (double)v.x + (double)v.y + (double)v.z + (double)v.w;
        q += (double)v.x * v.x + (double)v.y * v.y + (double)v.z * v.z + (double)v.w * v.w;
    }
    block_reduce2(s, q, S);
}

// ---- generic fold: gn(stats,g,bta) into conv weights; writes transposed w'[c][o], b'[o]
__global__ void k_fold(const double* __restrict__ S, const float* __restrict__ w,
                       const float* __restrict__ b, const float* __restrict__ g,
                       const float* __restrict__ bta,
                       float* __restrict__ wt, float* __restrict__ beff) {
    int o = blockIdx.x;
    float mu, inv; stats_from(S, &mu, &inv);
    float partial = 0.f;
    for (int c = threadIdx.x; c < CH; c += blockDim.x) {
        float sc = inv * g[c];
        float sh = bta[c] - mu * sc;
        float wv = w[o * CH + c];
        wt[c * CH + o] = wv * sc;
        partial += wv * sh;
    }
    #pragma unroll
    for (int off = 32; off > 0; off >>= 1) partial += __shfl_down(partial, off, 64);
    __shared__ float rp[2];
    int lane = threadIdx.x & 63, wv_ = threadIdx.x >> 6;
    if (lane == 0) rp[wv_] = partial;
    __syncthreads();
    if (threadIdx.x == 0) beff[o] = b[o] + rp[0] + rp[1];
}

// ---- fold n2 gn into fc1: fc1t[c][h], b1mlp[h]
__global__ void k_fold_fc1(const double* __restrict__ S, const float* __restrict__ fw,
                           const float* __restrict__ fb, const float* __restrict__ g,
                           const float* __restrict__ bta,
                           float* __restrict__ fc1t, float* __restrict__ b1m) {
    int h = blockIdx.x;
    float mu, inv; stats_from(S, &mu, &inv);
    float partial = 0.f;
    for (int c = threadIdx.x; c < CH; c += blockDim.x) {
        float sc = inv * g[c];
        float sh = bta[c] - mu * sc;
        float wv = fw[h * CH + c];
        fc1t[c * HID + h] = wv * sc;
        partial += wv * sh;
    }
    #pragma unroll
    for (int off = 32; off > 0; off >>= 1) partial += __shfl_down(partial, off, 64);
    __shared__ float rp[2];
    int lane = threadIdx.x & 63, wv_ = threadIdx.x >> 6;
    if (lane == 0) rp[wv_] = partial;
    __syncthreads();
    if (threadIdx.x == 0) b1m[h] = fb[h] + rp[0] + rp[1];
}

// ---- transposes (no stats deps): w2{d,h,w}t[c][o], fc2t[h][o]
__global__ void k_transpose(const float* __restrict__ w2d, const float* __restrict__ w2h,
                            const float* __restrict__ w2w, const float* __restrict__ fc2w,
                            float* __restrict__ w2dt, float* __restrict__ w2ht,
                            float* __restrict__ w2wt, float* __restrict__ fc2t) {
    int b = blockIdx.x;
    if (b < CH) {
        for (int c = threadIdx.x; c < CH; c += blockDim.x) {
            w2dt[c * CH + b] = w2d[b * CH + c];
            w2ht[c * CH + b] = w2h[b * CH + c];
            w2wt[c * CH + b] = w2w[b * CH + c];
        }
    }
    for (int o = threadIdx.x; o < CH; o += blockDim.x) {
        fc2t[b * CH + o] = fc2w[o * HID + b];
    }
}

// ---- K3: t = conv1'(x) (gn folded), + stats of t -> S1 ----
__global__ void __launch_bounds__(256)
k_conv1(const float* __restrict__ x, const float* __restrict__ w1t,
        const float* __restrict__ b1e, float* __restrict__ t, double* __restrict__ S1) {
    int lane = threadIdx.x & 63;
    int wv = __builtin_amdgcn_readfirstlane(threadIdx.x >> 6);
    int pos = blockIdx.x * 64 + lane;
    int ob = wv * 28;
    float acc[28];
    #pragma unroll
    for (int j = 0; j < 28; j++) acc[j] = 0.f;
    #pragma unroll 4
    for (int c = 0; c < CH; c++) {
        float v = x[c * NPOS + pos];
        const float* wr = w1t + c * CH + ob;
        #pragma unroll
        for (int j = 0; j < 28; j++) acc[j] += wr[j] * v;
    }
    double s = 0, q = 0;
    #pragma unroll
    for (int j = 0; j < 28; j++) {
        float tv = acc[j] + b1e[ob + j];
        t[(ob + j) * NPOS + pos] = tv;
        s += (double)tv; q += (double)tv * tv;
    }
    block_reduce2(s, q, S1);
}

// ---- K5: a = gelu(gn_affine(t)) in place ----
__global__ void k_act(float* __restrict__ t, const double* __restrict__ S1,
                      const float* __restrict__ g, const float* __restrict__ bta) {
    float mu, inv; stats_from(S1, &mu, &inv);
    int i4 = blockIdx.x * blockDim.x + threadIdx.x;   // float4 index; NELEM/4 total
    int c = i4 >> 16;                                  // 65536 float4 per channel
    float sc = inv * g[c], sh = bta[c] - mu * sc;
    float4* t4 = (float4*)t;
    float4 v = t4[i4];
    v.x = gelu_f(v.x * sc + sh);
    v.y = gelu_f(v.y * sc + sh);
    v.z = gelu_f(v.z * sc + sh);
    v.w = gelu_f(v.w * sc + sh);
    t4[i4] = v;
}

// ---- K6: s = sum of 3 shifted-conv-gelu branches, + stats -> S2 ----
__global__ void __launch_bounds__(256)
k_shift(const float* __restrict__ a,
        const float* __restrict__ w2dt, const float* __restrict__ b2d,
        const float* __restrict__ w2ht, const float* __restrict__ b2h,
        const float* __restrict__ w2wt, const float* __restrict__ b2w,
        float* __restrict__ sout, double* __restrict__ S2) {
    int lane = threadIdx.x & 63;
    int wv = __builtin_amdgcn_readfirstlane(threadIdx.x >> 6);
    int d = blockIdx.x >> 6, h = blockIdx.x & 63;
    int ob = wv * 28;
    float tot[28];
    #pragma unroll
    for (int j = 0; j < 28; j++) tot[j] = 0.f;

    float acc[28];
    // ---- branch D: a[c, d - s_c, h, w]
    #pragma unroll
    for (int j = 0; j < 28; j++) acc[j] = 0.f;
    #pragma unroll 2
    for (int c = 0; c < CH; c++) {
        int sft = (c >> 4) - 3;
        int dd = d - sft;
        float v = 0.f;
        if ((unsigned)dd < 64u) v = a[c * NPOS + dd * 4096 + h * 64 + lane];
        const float* wr = w2dt + c * CH + ob;
        #pragma unroll
        for (int j = 0; j < 28; j++) acc[j] += wr[j] * v;
    }
    #pragma unroll
    for (int j = 0; j < 28; j++) tot[j] += gelu_f(acc[j] + b2d[ob + j]);

    // ---- branch H: a[c, d-3, h-3-s_c, w-3]
    #pragma unroll
    for (int j = 0; j < 28; j++) acc[j] = 0.f;
    {
        int dd = d - 3;
        bool dok = (unsigned)dd < 64u;
        int ww = lane - 3;
        bool wok = (unsigned)ww < 64u;
        #pragma unroll 2
        for (int c = 0; c < CH; c++) {
            int sft = (c >> 4) - 3;
            int hh = h - 3 - sft;
            float v = 0.f;
            if (dok && wok && (unsigned)hh < 64u)
                v = a[c * NPOS + dd * 4096 + hh * 64 + ww];
            const float* wr = w2ht + c * CH + ob;
            #pragma unroll
            for (int j = 0; j < 28; j++) acc[j] += wr[j] * v;
        }
    }
    #pragma unroll
    for (int j = 0; j < 28; j++) tot[j] += gelu_f(acc[j] + b2h[ob + j]);

    // ---- branch W: a[c, d-6, h-6, w-6-s_c]
    #pragma unroll
    for (int j = 0; j < 28; j++) acc[j] = 0.f;
    {
        int dd = d - 6, hh = h - 6;
        bool ok = ((unsigned)dd < 64u) && ((unsigned)hh < 64u);
        #pragma unroll 2
        for (int c = 0; c < CH; c++) {
            int sft = (c >> 4) - 3;
            int ww = lane - 6 - sft;
            float v = 0.f;
            if (ok && (unsigned)ww < 64u)
                v = a[c * NPOS + dd * 4096 + hh * 64 + ww];
            const float* wr = w2wt + c * CH + ob;
            #pragma unroll
            for (int j = 0; j < 28; j++) acc[j] += wr[j] * v;
        }
    }
    #pragma unroll
    for (int j = 0; j < 28; j++) tot[j] += gelu_f(acc[j] + b2w[ob + j]);

    int pos = d * 4096 + h * 64 + lane;
    double s = 0, q = 0;
    #pragma unroll
    for (int j = 0; j < 28; j++) {
        float sv = tot[j];
        sout[(ob + j) * NPOS + pos] = sv;
        s += (double)sv; q += (double)sv * sv;
    }
    block_reduce2(s, q, S2);
}

// ---- K8: x1 = x + conv3'(s) + h0(x), + stats -> S3 ----
__global__ void __launch_bounds__(256)
k_comb(const float* __restrict__ sbuf, const float* __restrict__ x,
       const float* __restrict__ w3t, const float* __restrict__ b3e,
       const double* __restrict__ S0, const float* __restrict__ n1g,
       const float* __restrict__ n1b, float* __restrict__ x1, double* __restrict__ S3) {
    int lane = threadIdx.x & 63;
    int wv = __builtin_amdgcn_readfirstlane(threadIdx.x >> 6);
    int pos = blockIdx.x * 64 + lane;
    int ob = wv * 28;
    float acc[28];
    #pragma unroll
    for (int j = 0; j < 28; j++) acc[j] = 0.f;
    #pragma unroll 4
    for (int c = 0; c < CH; c++) {
        float v = sbuf[c * NPOS + pos];
        const float* wr = w3t + c * CH + ob;
        #pragma unroll
        for (int j = 0; j < 28; j++) acc[j] += wr[j] * v;
    }
    float mu, inv; stats_from(S0, &mu, &inv);
    double s = 0, q = 0;
    #pragma unroll
    for (int j = 0; j < 28; j++) {
        int o = ob + j;
        float y  = acc[j] + b3e[o];
        float xv = x[o * NPOS + pos];
        float sc = inv * n1g[o];
        float h0 = xv * sc + (n1b[o] - mu * sc);
        float v  = xv + y + h0;
        x1[o * NPOS + pos] = v;
        s += (double)v; q += (double)v * v;
    }
    block_reduce2(s, q, S3);
}

// ---- K10: out = x1 + fc2(gelu(fc1'(x1))), in place on x1 buffer ----
__global__ void __launch_bounds__(256)
k_mlp(float* __restrict__ x1out, const float* __restrict__ fc1t,
      const float* __restrict__ b1m, const float* __restrict__ fc2t,
      const float* __restrict__ fc2b) {
    __shared__ float lx[CH][64];
    __shared__ float lh[CH][64];
    int lane = threadIdx.x & 63;
    int wv = __builtin_amdgcn_readfirstlane(threadIdx.x >> 6);
    int pos = blockIdx.x * 64 + lane;
    int ob = wv * 28;
    #pragma unroll
    for (int r = 0; r < 28; r++) {
        int c = ob + r;
        lx[c][lane] = x1out[c * NPOS + pos];
    }
    __syncthreads();
    float outacc[28];
    #pragma unroll
    for (int j = 0; j < 28; j++) outacc[j] = 0.f;

    for (int hc = 0; hc < 4; hc++) {
        int hb = hc * 112 + ob;
        float hacc[28];
        #pragma unroll
        for (int j = 0; j < 28; j++) hacc[j] = b1m[hb + j];
        #pragma unroll 4
        for (int c = 0; c < CH; c++) {
            float v = lx[c][lane];
            const float* f1 = fc1t + c * HID + hb;
            #pragma unroll
            for (int j = 0; j < 28; j++) hacc[j] += f1[j] * v;
        }
        __syncthreads();   // prior phase-2 consumers done with lh
        #pragma unroll
        for (int j = 0; j < 28; j++) lh[ob + j][lane] = gelu_f(hacc[j]);
        __syncthreads();
        #pragma unroll 4
        for (int hh = 0; hh < CH; hh++) {
            float v = lh[hh][lane];
            const float* f2 = fc2t + (hc * 112 + hh) * CH + ob;
            #pragma unroll
            for (int j = 0; j < 28; j++) outacc[j] += f2[j] * v;
        }
    }
    #pragma unroll
    for (int j = 0; j < 28; j++) {
        int o = ob + j;
        float res = lx[o][lane] + outacc[j] + fc2b[o];
        x1out[o * NPOS + pos] = res;
    }
}

extern "C" void kernel_launch(void* const* d_in, const int* in_sizes, int n_in,
                              void* d_out, int out_size, void* d_ws, size_t ws_size,
                              hipStream_t stream) {
    const float* x       = (const float*)d_in[0];
    const float* conv1_w = (const float*)d_in[1];
    const float* conv1_b = (const float*)d_in[2];
    const float* conv2d_w= (const float*)d_in[3];
    const float* conv2d_b= (const float*)d_in[4];
    const float* conv2h_w= (const float*)d_in[5];
    const float* conv2h_b= (const float*)d_in[6];
    const float* conv2w_w= (const float*)d_in[7];
    const float* conv2w_b= (const float*)d_in[8];
    const float* conv3_w = (const float*)d_in[9];
    const float* conv3_b = (const float*)d_in[10];
    const float* fc1_w   = (const float*)d_in[11];
    const float* fc1_b   = (const float*)d_in[12];
    const float* fc2_w   = (const float*)d_in[13];
    const float* fc2_b   = (const float*)d_in[14];
    const float* n1_g    = (const float*)d_in[15];
    const float* n1_b    = (const float*)d_in[16];
    const float* na1_g   = (const float*)d_in[17];
    const float* na1_b   = (const float*)d_in[18];
    const float* na2_g   = (const float*)d_in[19];
    const float* na2_b   = (const float*)d_in[20];
    const float* n2_g    = (const float*)d_in[21];
    const float* n2_b    = (const float*)d_in[22];

    char* ws = (char*)d_ws;
    double* S = (double*)ws;                 // S0=S, S1=S+2, S2=S+4, S3=S+6
    float* prm  = (float*)(ws + 512);
    float* w1t  = prm;              // 12544
    float* b1e  = w1t  + 12544;     // 112
    float* w2dt = b1e  + 112;       // 12544
    float* w2ht = w2dt + 12544;     // 12544
    float* w2wt = w2ht + 12544;     // 12544
    float* w3t  = w2wt + 12544;     // 12544
    float* b3e  = w3t  + 12544;     // 112
    float* fc1t = b3e  + 112;       // 50176
    float* b1m  = fc1t + 50176;     // 448
    float* fc2t = b1m  + 448;       // 50176
    float* bufA = (float*)(ws + (1 << 20));  // 117,440,512 B
    float* out  = (float*)d_out;             // doubles as second big buffer

    hipMemsetAsync(S, 0, 8 * sizeof(double), stream);
    k_transpose<<<448, 128, 0, stream>>>(conv2d_w, conv2h_w, conv2w_w, fc2_w,
                                         w2dt, w2ht, w2wt, fc2t);
    k_reduce<<<1024, 256, 0, stream>>>(x, S);
    k_fold<<<112, 128, 0, stream>>>(S, conv1_w, conv1_b, n1_g, n1_b, w1t, b1e);
    k_conv1<<<4096, 256, 0, stream>>>(x, w1t, b1e, out, S + 2);
    k_act<<<28672, 256, 0, stream>>>(out, S + 2, na1_g, na1_b);
    k_shift<<<4096, 256, 0, stream>>>(out, w2dt, conv2d_b, w2ht, conv2h_b,
                                      w2wt, conv2w_b, bufA, S + 4);
    k_fold<<<112, 128, 0, stream>>>(S + 4, conv3_w, conv3_b, na2_g, na2_b, w3t, b3e);
    k_comb<<<4096, 256, 0, stream>>>(bufA, x, w3t, b3e, S, n1_g, n1_b, out, S + 6);
    k_fold_fc1<<<448, 128, 0, stream>>>(S + 6, fc1_w, fc1_b, n2_g, n2_b, fc1t, b1m);
    k_mlp<<<4096, 256, 0, stream>>>(out, fc1t, b1m, fc2t, fc2_b);
}

// Round 2
// 2149.978 us; speedup vs baseline: 1.4185x; 1.4185x over previous
//
#include <hip/hip_runtime.h>
#include <math.h>

static constexpr int CH   = 112;
static constexpr int HID  = 448;
static constexpr int NPOS = 64 * 64 * 64;            // 262144 = 2^18
static constexpr long long NELEM = (long long)CH * NPOS; // 29360128

__device__ __forceinline__ float gelu_f(float x) {
    return 0.5f * x * (1.0f + erff(x * 0.70710678118654752f));
}

// mean / inv-std from accumulated (sum, sumsq)
__device__ __forceinline__ void stats_from(const double* __restrict__ S, float* mu, float* inv) {
    double m = S[0] / (double)NELEM;
    double v = S[1] / (double)NELEM - m * m;
    *mu  = (float)m;
    *inv = (float)(1.0 / sqrt(v + 1e-5));
}

// block-wide (sum, sumsq) reduction -> atomicAdd into out[0], out[1]
__device__ __forceinline__ void block_reduce2(double s, double q, double* __restrict__ out) {
    #pragma unroll
    for (int off = 32; off > 0; off >>= 1) {
        s += __shfl_down(s, off, 64);
        q += __shfl_down(q, off, 64);
    }
    __shared__ double red[16];
    int lane = threadIdx.x & 63, wv = threadIdx.x >> 6;
    int nw = blockDim.x >> 6;
    if (lane == 0) { red[wv] = s; red[wv + 8] = q; }
    __syncthreads();
    if (threadIdx.x == 0) {
        double S = 0, Q = 0;
        for (int i = 0; i < nw; i++) { S += red[i]; Q += red[i + 8]; }
        atomicAdd(out, S);
        atomicAdd(out + 1, Q);
    }
}

// ---- K1: reduce x -> S0 ----
__global__ void k_reduce(const float* __restrict__ x, double* __restrict__ S) {
    long long i0 = (long long)blockIdx.x * blockDim.x + threadIdx.x;
    long long stride = (long long)gridDim.x * blockDim.x;
    const float4* x4 = (const float4*)x;
    long long n4 = NELEM / 4;
    double s = 0, q = 0;
    for (long long i = i0; i < n4; i += stride) {
        float4 v = x4[i];
        s += (double)v.x + (double)v.y + (double)v.z + (double)v.w;
        q += (double)v.x * v.x + (double)v.y * v.y + (double)v.z * v.z + (double)v.w * v.w;
    }
    block_reduce2(s, q, S);
}

// ---- generic fold: gn(stats,g,bta) into conv weights; writes transposed w'[c][o], b'[o]
__global__ void k_fold(const double* __restrict__ S, const float* __restrict__ w,
                       const float* __restrict__ b, const float* __restrict__ g,
                       const float* __restrict__ bta,
                       float* __restrict__ wt, float* __restrict__ beff) {
    int o = blockIdx.x;
    float mu, inv; stats_from(S, &mu, &inv);
    float partial = 0.f;
    for (int c = threadIdx.x; c < CH; c += blockDim.x) {
        float sc = inv * g[c];
        float sh = bta[c] - mu * sc;
        float wv = w[o * CH + c];
        wt[c * CH + o] = wv * sc;
        partial += wv * sh;
    }
    #pragma unroll
    for (int off = 32; off > 0; off >>= 1) partial += __shfl_down(partial, off, 64);
    __shared__ float rp[2];
    int lane = threadIdx.x & 63, wv_ = threadIdx.x >> 6;
    if (lane == 0) rp[wv_] = partial;
    __syncthreads();
    if (threadIdx.x == 0) beff[o] = b[o] + rp[0] + rp[1];
}

// ---- fold n2 gn into fc1: fc1t[c][h], b1mlp[h]
__global__ void k_fold_fc1(const double* __restrict__ S, const float* __restrict__ fw,
                           const float* __restrict__ fb, const float* __restrict__ g,
                           const float* __restrict__ bta,
                           float* __restrict__ fc1t, float* __restrict__ b1m) {
    int h = blockIdx.x;
    float mu, inv; stats_from(S, &mu, &inv);
    float partial = 0.f;
    for (int c = threadIdx.x; c < CH; c += blockDim.x) {
        float sc = inv * g[c];
        float sh = bta[c] - mu * sc;
        float wv = fw[h * CH + c];
        fc1t[c * HID + h] = wv * sc;
        partial += wv * sh;
    }
    #pragma unroll
    for (int off = 32; off > 0; off >>= 1) partial += __shfl_down(partial, off, 64);
    __shared__ float rp[2];
    int lane = threadIdx.x & 63, wv_ = threadIdx.x >> 6;
    if (lane == 0) rp[wv_] = partial;
    __syncthreads();
    if (threadIdx.x == 0) b1m[h] = fb[h] + rp[0] + rp[1];
}

// ---- transposes (no stats deps): w2{d,h,w}t[c][o], fc2t[h][o]
__global__ void k_transpose(const float* __restrict__ w2d, const float* __restrict__ w2h,
                            const float* __restrict__ w2w, const float* __restrict__ fc2w,
                            float* __restrict__ w2dt, float* __restrict__ w2ht,
                            float* __restrict__ w2wt, float* __restrict__ fc2t) {
    int b = blockIdx.x;
    if (b < CH) {
        for (int c = threadIdx.x; c < CH; c += blockDim.x) {
            w2dt[c * CH + b] = w2d[b * CH + c];
            w2ht[c * CH + b] = w2h[b * CH + c];
            w2wt[c * CH + b] = w2w[b * CH + c];
        }
    }
    for (int o = threadIdx.x; o < CH; o += blockDim.x) {
        fc2t[b * CH + o] = fc2w[o * HID + b];
    }
}

// ---- K3: t = conv1'(x) (gn folded), + stats of t -> S1 ----
// LDS-staged: block loads 112x64 x-tile once (coalesced float4), waves compute from LDS.
__global__ void __launch_bounds__(256)
k_conv1(const float* __restrict__ x, const float* __restrict__ w1t,
        const float* __restrict__ b1e, float* __restrict__ t, double* __restrict__ S1) {
    __shared__ float lx[CH][64];
    int lane = threadIdx.x & 63;
    int wv = __builtin_amdgcn_readfirstlane(threadIdx.x >> 6);
    int pos0 = blockIdx.x * 64;
    int ob = wv * 28;

    // stage tile
    {
        int c0 = threadIdx.x >> 4;         // 0..15
        int q  = threadIdx.x & 15;         // float4 idx within row
        #pragma unroll
        for (int p = 0; p < 7; p++) {
            int c = p * 16 + c0;
            float4 v = *(const float4*)(x + (long long)c * NPOS + pos0 + q * 4);
            *(float4*)(&lx[c][q * 4]) = v;
        }
    }
    __syncthreads();

    float acc[28];
    #pragma unroll
    for (int j = 0; j < 28; j++) acc[j] = 0.f;
    #pragma unroll 4
    for (int c = 0; c < CH; c++) {
        float v = lx[c][lane];
        const float* wr = w1t + c * CH + ob;
        #pragma unroll
        for (int j = 0; j < 28; j++) acc[j] += wr[j] * v;
    }
    double s = 0, q = 0;
    #pragma unroll
    for (int j = 0; j < 28; j++) {
        float tv = acc[j] + b1e[ob + j];
        t[(ob + j) * NPOS + pos0 + lane] = tv;
        s += (double)tv; q += (double)tv * tv;
    }
    block_reduce2(s, q, S1);
}

// ---- K5: a = gelu(gn_affine(t)) in place ----
__global__ void k_act(float* __restrict__ t, const double* __restrict__ S1,
                      const float* __restrict__ g, const float* __restrict__ bta) {
    float mu, inv; stats_from(S1, &mu, &inv);
    int i4 = blockIdx.x * blockDim.x + threadIdx.x;   // float4 index; NELEM/4 total
    int c = i4 >> 16;                                  // 65536 float4 per channel
    float sc = inv * g[c], sh = bta[c] - mu * sc;
    float4* t4 = (float4*)t;
    float4 v = t4[i4];
    v.x = gelu_f(v.x * sc + sh);
    v.y = gelu_f(v.y * sc + sh);
    v.z = gelu_f(v.z * sc + sh);
    v.w = gelu_f(v.w * sc + sh);
    t4[i4] = v;
}

// ---- K6: s = sum of 3 shifted-conv-gelu branches, + stats -> S2 ----
// LDS-staged per branch: the per-channel d/h row shifts are resolved at load
// time (zero-filled when out of range); only the w shift remains at compute.
__global__ void __launch_bounds__(256)
k_shift(const float* __restrict__ a,
        const float* __restrict__ w2dt, const float* __restrict__ b2d,
        const float* __restrict__ w2ht, const float* __restrict__ b2h,
        const float* __restrict__ w2wt, const float* __restrict__ b2w,
        float* __restrict__ sout, double* __restrict__ S2) {
    __shared__ float ls[CH][64];
    int lane = threadIdx.x & 63;
    int wv = __builtin_amdgcn_readfirstlane(threadIdx.x >> 6);
    int d = blockIdx.x >> 6, h = blockIdx.x & 63;
    int ob = wv * 28;
    int c0 = threadIdx.x >> 4;         // loader: channel sub-index 0..15
    int qq = threadIdx.x & 15;         // loader: float4 within row

    float tot[28];
    #pragma unroll
    for (int j = 0; j < 28; j++) tot[j] = 0.f;
    float acc[28];

    // ================= branch D: a[c, d - s_c, h, lane] =================
    #pragma unroll
    for (int p = 0; p < 7; p++) {
        int c = p * 16 + c0;
        int sft = (c >> 4) - 3;
        int dd = d - sft;
        float4 v = make_float4(0.f, 0.f, 0.f, 0.f);
        if ((unsigned)dd < 64u)
            v = *(const float4*)(a + (long long)c * NPOS + dd * 4096 + h * 64 + qq * 4);
        *(float4*)(&ls[c][qq * 4]) = v;
    }
    __syncthreads();
    #pragma unroll
    for (int j = 0; j < 28; j++) acc[j] = 0.f;
    #pragma unroll 4
    for (int c = 0; c < CH; c++) {
        float v = ls[c][lane];
        const float* wr = w2dt + c * CH + ob;
        #pragma unroll
        for (int j = 0; j < 28; j++) acc[j] += wr[j] * v;
    }
    #pragma unroll
    for (int j = 0; j < 28; j++) tot[j] += gelu_f(acc[j] + b2d[ob + j]);
    __syncthreads();

    // ================= branch H: a[c, d-3, h-3-s_c, lane-3] =================
    {
        int dd = d - 3;
        bool dok = (unsigned)dd < 64u;
        #pragma unroll
        for (int p = 0; p < 7; p++) {
            int c = p * 16 + c0;
            int sft = (c >> 4) - 3;
            int hh = h - 3 - sft;
            float4 v = make_float4(0.f, 0.f, 0.f, 0.f);
            if (dok && (unsigned)hh < 64u)
                v = *(const float4*)(a + (long long)c * NPOS + dd * 4096 + hh * 64 + qq * 4);
            *(float4*)(&ls[c][qq * 4]) = v;
        }
    }
    __syncthreads();
    #pragma unroll
    for (int j = 0; j < 28; j++) acc[j] = 0.f;
    {
        int wi = lane - 3;
        bool wok = wi >= 0;
        #pragma unroll 4
        for (int c = 0; c < CH; c++) {
            float v = wok ? ls[c][wi & 63] : 0.f;
            const float* wr = w2ht + c * CH + ob;
            #pragma unroll
            for (int j = 0; j < 28; j++) acc[j] += wr[j] * v;
        }
    }
    #pragma unroll
    for (int j = 0; j < 28; j++) tot[j] += gelu_f(acc[j] + b2h[ob + j]);
    __syncthreads();

    // ================= branch W: a[c, d-6, h-6, lane-6-s_c] =================
    {
        int dd = d - 6, hh = h - 6;
        bool ok = ((unsigned)dd < 64u) && ((unsigned)hh < 64u);
        #pragma unroll
        for (int p = 0; p < 7; p++) {
            int c = p * 16 + c0;
            float4 v = make_float4(0.f, 0.f, 0.f, 0.f);
            if (ok)
                v = *(const float4*)(a + (long long)c * NPOS + dd * 4096 + hh * 64 + qq * 4);
            *(float4*)(&ls[c][qq * 4]) = v;
        }
    }
    __syncthreads();
    #pragma unroll
    for (int j = 0; j < 28; j++) acc[j] = 0.f;
    #pragma unroll 4
    for (int c = 0; c < CH; c++) {
        int sft = (c >> 4) - 3;
        int wi = lane - 6 - sft;
        float v = ((unsigned)wi < 64u) ? ls[c][wi & 63] : 0.f;
        const float* wr = w2wt + c * CH + ob;
        #pragma unroll
        for (int j = 0; j < 28; j++) acc[j] += wr[j] * v;
    }
    #pragma unroll
    for (int j = 0; j < 28; j++) tot[j] += gelu_f(acc[j] + b2w[ob + j]);

    int pos = d * 4096 + h * 64 + lane;
    double s = 0, q = 0;
    #pragma unroll
    for (int j = 0; j < 28; j++) {
        float sv = tot[j];
        sout[(ob + j) * NPOS + pos] = sv;
        s += (double)sv; q += (double)sv * sv;
    }
    block_reduce2(s, q, S2);
}

// ---- K8: x1 = x + conv3'(s) + h0(x), + stats -> S3 ----
__global__ void __launch_bounds__(256)
k_comb(const float* __restrict__ sbuf, const float* __restrict__ x,
       const float* __restrict__ w3t, const float* __restrict__ b3e,
       const double* __restrict__ S0, const float* __restrict__ n1g,
       const float* __restrict__ n1b, float* __restrict__ x1, double* __restrict__ S3) {
    __shared__ float ls[CH][64];
    int lane = threadIdx.x & 63;
    int wv = __builtin_amdgcn_readfirstlane(threadIdx.x >> 6);
    int pos0 = blockIdx.x * 64;
    int ob = wv * 28;

    {
        int c0 = threadIdx.x >> 4;
        int qq = threadIdx.x & 15;
        #pragma unroll
        for (int p = 0; p < 7; p++) {
            int c = p * 16 + c0;
            float4 v = *(const float4*)(sbuf + (long long)c * NPOS + pos0 + qq * 4);
            *(float4*)(&ls[c][qq * 4]) = v;
        }
    }
    __syncthreads();

    float acc[28];
    #pragma unroll
    for (int j = 0; j < 28; j++) acc[j] = 0.f;
    #pragma unroll 4
    for (int c = 0; c < CH; c++) {
        float v = ls[c][lane];
        const float* wr = w3t + c * CH + ob;
        #pragma unroll
        for (int j = 0; j < 28; j++) acc[j] += wr[j] * v;
    }
    float mu, inv; stats_from(S0, &mu, &inv);
    double s = 0, q = 0;
    #pragma unroll
    for (int j = 0; j < 28; j++) {
        int o = ob + j;
        float y  = acc[j] + b3e[o];
        float xv = x[(long long)o * NPOS + pos0 + lane];
        float sc = inv * n1g[o];
        float h0 = xv * sc + (n1b[o] - mu * sc);
        float v  = xv + y + h0;
        x1[(long long)o * NPOS + pos0 + lane] = v;
        s += (double)v; q += (double)v * v;
    }
    block_reduce2(s, q, S3);
}

// ---- K10: out = x1 + fc2(gelu(fc1'(x1))), in place on x1 buffer ----
__global__ void __launch_bounds__(256)
k_mlp(float* __restrict__ x1out, const float* __restrict__ fc1t,
      const float* __restrict__ b1m, const float* __restrict__ fc2t,
      const float* __restrict__ fc2b) {
    __shared__ float lx[CH][64];
    __shared__ float lh[CH][64];
    int lane = threadIdx.x & 63;
    int wv = __builtin_amdgcn_readfirstlane(threadIdx.x >> 6);
    int pos0 = blockIdx.x * 64;
    int ob = wv * 28;
    {
        int c0 = threadIdx.x >> 4;
        int qq = threadIdx.x & 15;
        #pragma unroll
        for (int p = 0; p < 7; p++) {
            int c = p * 16 + c0;
            float4 v = *(const float4*)(x1out + (long long)c * NPOS + pos0 + qq * 4);
            *(float4*)(&lx[c][qq * 4]) = v;
        }
    }
    __syncthreads();
    float outacc[28];
    #pragma unroll
    for (int j = 0; j < 28; j++) outacc[j] = 0.f;

    for (int hc = 0; hc < 4; hc++) {
        int hb = hc * 112 + ob;
        float hacc[28];
        #pragma unroll
        for (int j = 0; j < 28; j++) hacc[j] = b1m[hb + j];
        #pragma unroll 4
        for (int c = 0; c < CH; c++) {
            float v = lx[c][lane];
            const float* f1 = fc1t + c * HID + hb;
            #pragma unroll
            for (int j = 0; j < 28; j++) hacc[j] += f1[j] * v;
        }
        __syncthreads();   // prior phase-2 consumers done with lh
        #pragma unroll
        for (int j = 0; j < 28; j++) lh[ob + j][lane] = gelu_f(hacc[j]);
        __syncthreads();
        #pragma unroll 4
        for (int hh = 0; hh < CH; hh++) {
            float v = lh[hh][lane];
            const float* f2 = fc2t + (hc * 112 + hh) * CH + ob;
            #pragma unroll
            for (int j = 0; j < 28; j++) outacc[j] += f2[j] * v;
        }
    }
    #pragma unroll
    for (int j = 0; j < 28; j++) {
        int o = ob + j;
        float res = lx[o][lane] + outacc[j] + fc2b[o];
        x1out[(long long)o * NPOS + pos0 + lane] = res;
    }
}

extern "C" void kernel_launch(void* const* d_in, const int* in_sizes, int n_in,
                              void* d_out, int out_size, void* d_ws, size_t ws_size,
                              hipStream_t stream) {
    const float* x       = (const float*)d_in[0];
    const float* conv1_w = (const float*)d_in[1];
    const float* conv1_b = (const float*)d_in[2];
    const float* conv2d_w= (const float*)d_in[3];
    const float* conv2d_b= (const float*)d_in[4];
    const float* conv2h_w= (const float*)d_in[5];
    const float* conv2h_b= (const float*)d_in[6];
    const float* conv2w_w= (const float*)d_in[7];
    const float* conv2w_b= (const float*)d_in[8];
    const float* conv3_w = (const float*)d_in[9];
    const float* conv3_b = (const float*)d_in[10];
    const float* fc1_w   = (const float*)d_in[11];
    const float* fc1_b   = (const float*)d_in[12];
    const float* fc2_w   = (const float*)d_in[13];
    const float* fc2_b   = (const float*)d_in[14];
    const float* n1_g    = (const float*)d_in[15];
    const float* n1_b    = (const float*)d_in[16];
    const float* na1_g   = (const float*)d_in[17];
    const float* na1_b   = (const float*)d_in[18];
    const float* na2_g   = (const float*)d_in[19];
    const float* na2_b   = (const float*)d_in[20];
    const float* n2_g    = (const float*)d_in[21];
    const float* n2_b    = (const float*)d_in[22];

    char* ws = (char*)d_ws;
    double* S = (double*)ws;                 // S0=S, S1=S+2, S2=S+4, S3=S+6
    float* prm  = (float*)(ws + 512);
    float* w1t  = prm;              // 12544
    float* b1e  = w1t  + 12544;     // 112
    float* w2dt = b1e  + 112;       // 12544
    float* w2ht = w2dt + 12544;     // 12544
    float* w2wt = w2ht + 12544;     // 12544
    float* w3t  = w2wt + 12544;     // 12544
    float* b3e  = w3t  + 12544;     // 112
    float* fc1t = b3e  + 112;       // 50176
    float* b1m  = fc1t + 50176;     // 448
    float* fc2t = b1m  + 448;       // 50176
    float* bufA = (float*)(ws + (1 << 20));  // 117,440,512 B
    float* out  = (float*)d_out;             // doubles as second big buffer

    hipMemsetAsync(S, 0, 8 * sizeof(double), stream);
    k_transpose<<<448, 128, 0, stream>>>(conv2d_w, conv2h_w, conv2w_w, fc2_w,
                                         w2dt, w2ht, w2wt, fc2t);
    k_reduce<<<1024, 256, 0, stream>>>(x, S);
    k_fold<<<112, 128, 0, stream>>>(S, conv1_w, conv1_b, n1_g, n1_b, w1t, b1e);
    k_conv1<<<4096, 256, 0, stream>>>(x, w1t, b1e, out, S + 2);
    k_act<<<28672, 256, 0, stream>>>(out, S + 2, na1_g, na1_b);
    k_shift<<<4096, 256, 0, stream>>>(out, w2dt, conv2d_b, w2ht, conv2h_b,
                                      w2wt, conv2w_b, bufA, S + 4);
    k_fold<<<112, 128, 0, stream>>>(S + 4, conv3_w, conv3_b, na2_g, na2_b, w3t, b3e);
    k_comb<<<4096, 256, 0, stream>>>(bufA, x, w3t, b3e, S, n1_g, n1_b, out, S + 6);
    k_fold_fc1<<<448, 128, 0, stream>>>(S + 6, fc1_w, fc1_b, n2_g, n2_b, fc1t, b1m);
    k_mlp<<<4096, 256, 0, stream>>>(out, fc1t, b1m, fc2t, fc2_b);
}